// Round 6
// baseline (634.427 us; speedup 1.0000x reference)
//
#include <hip/hip_runtime.h>

#define BS  16
#define TT  50
#define NN  100
#define OBSF 40
#define ACTF 8
#define HIDF 64
#define LATF 16

typedef __attribute__((ext_vector_type(8))) short bf16x8;
typedef __attribute__((ext_vector_type(4))) float f32x4;

__device__ __forceinline__ float sigmf(float x) { return 1.f / (1.f + __expf(-x)); }
__device__ __forceinline__ float tanh_fast(float x) { return 1.f - 2.f / (__expf(2.f * x) + 1.f); }

// pack two fp32 -> two bf16 (RNE) in one dword
__device__ __forceinline__ unsigned bf16pk_rne(float a, float b) {
    unsigned ua = __float_as_uint(a); ua += 0x7fffu + ((ua >> 16) & 1u);
    unsigned ub = __float_as_uint(b); ub += 0x7fffu + ((ub >> 16) & 1u);
    return (ua >> 16) | (ub & 0xffff0000u);
}
// truncation pack (used for P; denom sums the SAME truncated values)
__device__ __forceinline__ unsigned bf16pk_trunc(float a, float b) {
    return (__float_as_uint(a) >> 16) | (__float_as_uint(b) & 0xffff0000u);
}
__device__ __forceinline__ float bf16trunc_f(float a) {
    return __uint_as_float(__float_as_uint(a) & 0xffff0000u);
}

// ---------------------------------------------------------------- adj masks
// mask: ull[2] per row (VALU GAT); mask32: uint[4] per row, rows padded to 112
__global__ void adjmask_kernel(const int* __restrict__ adj, unsigned long long* __restrict__ mask,
                               unsigned* __restrict__ mask32) {
    int n = threadIdx.x;
    if (n < 112) {
        unsigned d0 = 0, d1 = 0, d2 = 0, d3 = 0;
        if (n < NN) {
            for (int m = 0; m < NN; ++m) {
                if (adj[n * NN + m] > 0) {
                    if (m < 32) d0 |= 1u << m;
                    else if (m < 64) d1 |= 1u << (m - 32);
                    else if (m < 96) d2 |= 1u << (m - 64);
                    else d3 |= 1u << (m - 96);
                }
            }
        }
        mask32[n * 4 + 0] = d0; mask32[n * 4 + 1] = d1;
        mask32[n * 4 + 2] = d2; mask32[n * 4 + 3] = d3;
        if (n < NN) {
            mask[2 * n] = (unsigned long long)d0 | ((unsigned long long)d1 << 32);
            mask[2 * n + 1] = (unsigned long long)d2 | ((unsigned long long)d3 << 32);
        }
    }
}

// ---------------------------------------------------------------- embedding
__global__ void emb_kernel(const float* __restrict__ o, const float* __restrict__ ap,
                           const float* __restrict__ mk,
                           const float* __restrict__ Wobs, const float* __restrict__ bobs,
                           const float* __restrict__ Wpa, const float* __restrict__ bpa,
                           const float* __restrict__ Wmk, const float* __restrict__ bmk,
                           const float* __restrict__ idemb, float* __restrict__ emb) {
    int g = blockIdx.x;               // (b*T+t)*N + n
    int n = g % NN;
    int j = threadIdx.x;              // 0..63
    __shared__ float so[OBSF], sa[ACTF], sm[ACTF];
    if (j < OBSF) so[j] = o[(size_t)g * OBSF + j];
    if (j >= 40 && j < 48) sa[j - 40] = ap[(size_t)g * ACTF + (j - 40)];
    if (j >= 48 && j < 56) sm[j - 48] = mk[(size_t)g * ACTF + (j - 48)];
    __syncthreads();
    float acc = bobs[j] + bpa[j] + bmk[j] + idemb[n * HIDF + j];
    #pragma unroll
    for (int k = 0; k < OBSF; ++k) acc += so[k] * Wobs[k * HIDF + j];
    #pragma unroll
    for (int k = 0; k < ACTF; ++k) acc += sa[k] * Wpa[k * HIDF + j] + sm[k] * Wmk[k * HIDF + j];
    emb[(size_t)g * HIDF + j] = acc;
}

// ---------------------------------------------------------------- xW = x @ Wih + bih + bhh
__global__ void xw_kernel(const float* __restrict__ emb, const float* __restrict__ Wih,
                          const float* __restrict__ bih, const float* __restrict__ bhh,
                          float* __restrict__ xW) {
    int blk = blockIdx.x;
    int chunk = blk % 5;
    int s = blk / 5;
    int b = s / NN, n = s % NN;
    int t0 = chunk * 10;
    __shared__ float se[10][HIDF];
    int tid = threadIdx.x;
    for (int i = tid; i < 10 * HIDF; i += 256) {
        int r = i >> 6, k = i & 63;
        se[r][k] = emb[((size_t)(b * TT + t0 + r) * NN + n) * HIDF + k];
    }
    __syncthreads();
    int j = tid;
    float base = bih[j] + bhh[j];
    float acc[10];
    #pragma unroll
    for (int r = 0; r < 10; ++r) acc[r] = base;
    for (int k = 0; k < HIDF; ++k) {
        float w = Wih[k * 256 + j];
        #pragma unroll
        for (int r = 0; r < 10; ++r) acc[r] += se[r][k] * w;
    }
    #pragma unroll
    for (int r = 0; r < 10; ++r) xW[((size_t)s * TT + t0 + r) * 256 + j] = acc[r];
}

// ---------------------------------------------------------------- LSTM recurrence (round-2 structure)
__launch_bounds__(256)
__global__ void lstm_kernel(const float* __restrict__ xW, const float* __restrict__ Whh,
                            float* __restrict__ xenc) {
    int s = blockIdx.x;
    int b = s / NN, n = s % NN;
    int j = threadIdx.x;
    __shared__ __align__(16) float hs[HIDF];
    __shared__ float gs[256];
    float wcol[HIDF];
    #pragma unroll
    for (int k = 0; k < HIDF; ++k) wcol[k] = Whh[k * 256 + j];
    if (j < HIDF) hs[j] = 0.f;
    float c = 0.f;
    __syncthreads();
    for (int t = 0; t < TT; ++t) {
        float acc = xW[((size_t)s * TT + t) * 256 + j];
        const float4* h4 = (const float4*)hs;
        #pragma unroll
        for (int k4 = 0; k4 < HIDF / 4; ++k4) {
            float4 hv = h4[k4];
            acc += hv.x * wcol[4 * k4] + hv.y * wcol[4 * k4 + 1]
                 + hv.z * wcol[4 * k4 + 2] + hv.w * wcol[4 * k4 + 3];
        }
        gs[j] = acc;
        __syncthreads();
        if (j < HIDF) {
            float ig = sigmf(gs[j]);
            float fg = sigmf(gs[64 + j]);
            float gg = tanh_fast(gs[128 + j]);
            float og = sigmf(gs[192 + j]);
            c = fg * c + ig * gg;
            float h = og * tanh_fast(c);
            hs[j] = h;
            xenc[((size_t)(b * TT + t) * NN + n) * HIDF + j] = h;
        }
        __syncthreads();
    }
}

// ---------------------------------------------------------------- MFMA GAT (H=4, FOUT=16, concat+ELU)
// wave w owns head w. Phase 1: h = x@w via mfma_16x16x32_bf16 (7 M-tiles).
// e_src/e_dst from C-frags by shfl reduction. Phase 2: P built in A-frag regs
// (exp fp32, trunc->bf16; denom from same truncated values), 28 MFMAs, then
// epilogue divide+bias+elu. LDS rows padded +8 bf16 to kill bank conflicts.
// NOTE: sh2 pad columns [112,128) MUST be fully zeroed — stale LDS there
// enters phase-2 B fragments and 0*garbage can be NaN (round-5 bug).
template <int FIN1, int FIN2>
__launch_bounds__(256)
__global__ void gat4_mfma_kernel(const float* __restrict__ x1, const float* __restrict__ x2,
                                 const float* __restrict__ w, const float* __restrict__ asrc,
                                 const float* __restrict__ adst, const float* __restrict__ bias,
                                 const unsigned* __restrict__ mask32, float* __restrict__ out) {
    constexpr int FIN = FIN1 + FIN2;
    constexpr int FINP = (FIN + 31) & ~31;           // 64 or 96
    constexpr int KC1 = FINP / 32;
    constexpr int SXP = FINP + 8;                    // padded strides (bf16 elems)
    constexpr int SWP = FINP + 8;
    constexpr int SH2P = 136;                        // 128 + 8
    constexpr int R1A = 112 * SXP * 2;
    constexpr int R1B = 4 * 16 * SH2P * 2;           // 17408
    constexpr int R1 = (R1A > R1B) ? R1A : R1B;
    constexpr int R2A = 64 * SWP * 2;
    constexpr int R2B = (448 + 512 + 448 + 448) * 4; // ses+sed+sden+smk = 7424
    constexpr int R2 = (R2A > R2B) ? R2A : R2B;
    __shared__ __align__(16) char smem[R1 + R2];
    short* sxa = (short*)smem;                       // [112][SXP]
    short* sh2 = (short*)smem;                       // alias: [4][16][SH2P]
    short* swb = (short*)(smem + R1);                // [64][SWP]
    float* ses = (float*)(smem + R1);                // alias: [4][112]
    float* sed = ses + 448;                          // [4][128]
    float* sden = sed + 512;                         // [4][112]
    unsigned* smk = (unsigned*)(sden + 448);         // [112][4]

    const int g = blockIdx.x, tid = threadIdx.x;
    const int wv = tid >> 6, lane = tid & 63, q = lane >> 4, c = lane & 15;
    const int head = wv;

    // ---- stage x (A, bf16, zero-padded) and w (B^T, bf16)
    for (int i = tid; i < 112 * (SXP / 2); i += 256) {
        int n = i / (SXP / 2), k2 = i % (SXP / 2);
        int k = 2 * k2;
        float lo = 0.f, hi = 0.f;
        if (n < NN) {
            if (k < FIN1) {
                float2 v = *(const float2*)&x1[((size_t)g * NN + n) * FIN1 + k];
                lo = v.x; hi = v.y;
            } else if (FIN2 > 0 && k < FIN) {
                float2 v = *(const float2*)&x2[(size_t)g * FIN2 + (k - FIN1)];
                lo = v.x; hi = v.y;
            }
        }
        ((unsigned*)sxa)[i] = bf16pk_rne(lo, hi);
    }
    for (int i = tid; i < 64 * (SWP / 2); i += 256) {
        int nc = i / (SWP / 2), k2 = i % (SWP / 2);
        int h = nc >> 4, o = nc & 15, k = 2 * k2;
        float lo = 0.f, hi = 0.f;
        if (k < FIN) {
            lo = w[((size_t)h * FIN + k) * 16 + o];
            if (k + 1 < FIN) hi = w[((size_t)h * FIN + k + 1) * 16 + o];
        }
        ((unsigned*)swb)[i] = bf16pk_rne(lo, hi);
    }
    __syncthreads();

    // ---- phase 1 MFMA: h = x @ w
    const float asv = asrc[head * 16 + c], adv = adst[head * 16 + c];
    const float biasv = bias[head * 16 + c];
    f32x4 hc[7];
    #pragma unroll
    for (int mt = 0; mt < 7; ++mt) hc[mt] = f32x4{0.f, 0.f, 0.f, 0.f};
    #pragma unroll
    for (int kc = 0; kc < KC1; ++kc) {
        bf16x8 bfr = *(const bf16x8*)&swb[(head * 16 + c) * SWP + kc * 32 + q * 8];
        #pragma unroll
        for (int mt = 0; mt < 7; ++mt) {
            bf16x8 afr = *(const bf16x8*)&sxa[(mt * 16 + c) * SXP + kc * 32 + q * 8];
            hc[mt] = __builtin_amdgcn_mfma_f32_16x16x32_bf16(afr, bfr, hc[mt], 0, 0, 0);
        }
    }
    __syncthreads();   // sxa/swb dead; regions become sh2 / ses..smk

    // ---- epilogue 1: h -> sh2 (bf16, B-layout), e_src/e_dst via shfl
    #pragma unroll
    for (int mt = 0; mt < 7; ++mt) {
        float h0 = hc[mt][0], h1 = hc[mt][1], h2 = hc[mt][2], h3 = hc[mt][3];
        uint2 pk;
        pk.x = bf16pk_rne(h0, h1);
        pk.y = bf16pk_rne(h2, h3);
        *(uint2*)&sh2[(head * 16 + c) * SH2P + mt * 16 + q * 4] = pk;
        float es0 = h0 * asv, es1 = h1 * asv, es2 = h2 * asv, es3 = h3 * asv;
        float ed0 = h0 * adv, ed1 = h1 * adv, ed2 = h2 * adv, ed3 = h3 * adv;
        #pragma unroll
        for (int off = 1; off <= 8; off <<= 1) {
            es0 += __shfl_xor(es0, off, 64); es1 += __shfl_xor(es1, off, 64);
            es2 += __shfl_xor(es2, off, 64); es3 += __shfl_xor(es3, off, 64);
            ed0 += __shfl_xor(ed0, off, 64); ed1 += __shfl_xor(ed1, off, 64);
            ed2 += __shfl_xor(ed2, off, 64); ed3 += __shfl_xor(ed3, off, 64);
        }
        if (c == 0) {
            int nb = mt * 16 + q * 4;
            ses[head * 112 + nb + 0] = es0; ses[head * 112 + nb + 1] = es1;
            ses[head * 112 + nb + 2] = es2; ses[head * 112 + nb + 3] = es3;
            sed[head * 128 + nb + 0] = ed0; sed[head * 128 + nb + 1] = ed1;
            sed[head * 128 + nb + 2] = ed2; sed[head * 128 + nb + 3] = ed3;
        }
    }
    if (lane < 16) {
        // zero sh2 columns [112,128) (ALL 16 shorts) and sed [112,128)
        uint4 z4 = {0u, 0u, 0u, 0u};
        *(uint4*)&sh2[(head * 16 + lane) * SH2P + 112] = z4;
        *(uint4*)&sh2[(head * 16 + lane) * SH2P + 120] = z4;
        sed[head * 128 + 112 + lane] = 0.f;
    }
    for (int i = tid; i < 448; i += 256) smk[i] = mask32[i];
    __syncthreads();

    // ---- phase 2: P (A-frag regs) x H (sh2) via MFMA
    float esr[7];
    #pragma unroll
    for (int mt = 0; mt < 7; ++mt) esr[mt] = ses[head * 112 + mt * 16 + c];
    f32x4 c2[7];
    float dnp[7];
    #pragma unroll
    for (int mt = 0; mt < 7; ++mt) { c2[mt] = f32x4{0.f, 0.f, 0.f, 0.f}; dnp[mt] = 0.f; }
    #pragma unroll
    for (int kc = 0; kc < 4; ++kc) {
        float4 edA = *(const float4*)&sed[head * 128 + kc * 32 + q * 8];
        float4 edB = *(const float4*)&sed[head * 128 + kc * 32 + q * 8 + 4];
        bf16x8 bfr = *(const bf16x8*)&sh2[(head * 16 + c) * SH2P + kc * 32 + q * 8];
        #pragma unroll
        for (int mt = 0; mt < 7; ++mt) {
            unsigned mrow = smk[(mt * 16 + c) * 4 + kc];
            unsigned mb = (mrow >> (q * 8)) & 0xffu;
            float es = esr[mt];
            float e0 = es + edA.x; e0 = fmaxf(e0, 0.2f * e0);
            float e1 = es + edA.y; e1 = fmaxf(e1, 0.2f * e1);
            float e2 = es + edA.z; e2 = fmaxf(e2, 0.2f * e2);
            float e3 = es + edA.w; e3 = fmaxf(e3, 0.2f * e3);
            float e4 = es + edB.x; e4 = fmaxf(e4, 0.2f * e4);
            float e5 = es + edB.y; e5 = fmaxf(e5, 0.2f * e5);
            float e6 = es + edB.z; e6 = fmaxf(e6, 0.2f * e6);
            float e7 = es + edB.w; e7 = fmaxf(e7, 0.2f * e7);
            float p0 = (mb & 1u)   ? __expf(e0) : 0.f;
            float p1 = (mb & 2u)   ? __expf(e1) : 0.f;
            float p2 = (mb & 4u)   ? __expf(e2) : 0.f;
            float p3 = (mb & 8u)   ? __expf(e3) : 0.f;
            float p4 = (mb & 16u)  ? __expf(e4) : 0.f;
            float p5 = (mb & 32u)  ? __expf(e5) : 0.f;
            float p6 = (mb & 64u)  ? __expf(e6) : 0.f;
            float p7 = (mb & 128u) ? __expf(e7) : 0.f;
            union { unsigned u[4]; bf16x8 v; } af;
            af.u[0] = bf16pk_trunc(p0, p1);
            af.u[1] = bf16pk_trunc(p2, p3);
            af.u[2] = bf16pk_trunc(p4, p5);
            af.u[3] = bf16pk_trunc(p6, p7);
            dnp[mt] += ((bf16trunc_f(p0) + bf16trunc_f(p1)) + (bf16trunc_f(p2) + bf16trunc_f(p3)))
                     + ((bf16trunc_f(p4) + bf16trunc_f(p5)) + (bf16trunc_f(p6) + bf16trunc_f(p7)));
            c2[mt] = __builtin_amdgcn_mfma_f32_16x16x32_bf16(af.v, bfr, c2[mt], 0, 0, 0);
        }
    }
    // denom reduce across quads (rows indexed by c)
    #pragma unroll
    for (int mt = 0; mt < 7; ++mt) {
        float d = dnp[mt];
        d += __shfl_xor(d, 16, 64);
        d += __shfl_xor(d, 32, 64);
        if (q == 0) sden[head * 112 + mt * 16 + c] = d;
    }
    // same-wave producer/consumer: lgkmcnt wait inserted by compiler
    #pragma unroll
    for (int mt = 0; mt < 7; ++mt) {
        float4 dv = *(const float4*)&sden[head * 112 + mt * 16 + q * 4];
        float dvr[4] = {dv.x, dv.y, dv.z, dv.w};
        #pragma unroll
        for (int r = 0; r < 4; ++r) {
            int n = mt * 16 + q * 4 + r;
            if (n < NN) {
                float v = c2[mt][r] / dvr[r] + biasv;
                v = (v > 0.f) ? v : (__expf(v) - 1.f);
                out[((size_t)g * NN + n) * 64 + head * 16 + c] = v;
            }
        }
    }
}

// ---------------------------------------------------------------- VALU GAT (H=1 layers)
// OUTMODE 1: single head + bias; 2: +bias then * mgate
template <int FIN1, int FIN2, int H, int FOUT, int SPLIT, int OUTMODE>
__launch_bounds__(256)
__global__ void gat_kernel(const float* __restrict__ x1, const float* __restrict__ x2,
                           const float* __restrict__ w, const float* __restrict__ asrc,
                           const float* __restrict__ adst, const float* __restrict__ bias,
                           const unsigned long long* __restrict__ adjmask,
                           const float* __restrict__ mgate, float* __restrict__ out) {
    constexpr int FIN = FIN1 + FIN2;
    constexpr int HF = H * FOUT;
    constexpr int NPT = 256 / HF;
    constexpr int ROWS = (NN + NPT - 1) / NPT;
    constexpr int SB = NN * (FIN > HF ? FIN : HF);
    __shared__ __align__(16) float sbuf[SB];
    __shared__ __align__(16) float ses[H * NN];
    __shared__ __align__(16) float sed[H * NN];
    __shared__ unsigned long long smask[2 * NN];
    int g = blockIdx.x;
    int tid = threadIdx.x;

    for (int i = tid; i < NN * FIN1; i += 256) {
        int n = i / FIN1, k = i % FIN1;
        sbuf[n * FIN + k] = x1[((size_t)g * NN + n) * FIN1 + k];
    }
    if constexpr (FIN2 > 0) {
        for (int i = tid; i < NN * FIN2; i += 256) {
            int n = i / FIN2, k = i % FIN2;
            sbuf[n * FIN + FIN1 + k] = x2[(size_t)g * FIN2 + k];
        }
    }
    if (tid < 2 * NN) smask[tid] = adjmask[tid];
    __syncthreads();

    const int ho = tid % HF;
    const int h = ho / FOUT, o = ho % FOUT;
    const int n0 = tid / HF;
    float racc[ROWS];
    {
        float wcol[FIN];
        #pragma unroll
        for (int k = 0; k < FIN; ++k) wcol[k] = w[(h * FIN + k) * FOUT + o];
        const float as = asrc[ho], ad = adst[ho];
        #pragma unroll
        for (int r = 0; r < ROWS; ++r) {
            int n = n0 + r * NPT;
            float acc = 0.f;
            if (ROWS * NPT == NN || n < NN) {
                const float4* row = (const float4*)&sbuf[n * FIN];
                #pragma unroll
                for (int k4 = 0; k4 < FIN / 4; ++k4) {
                    float4 xv = row[k4];
                    acc += xv.x * wcol[4 * k4] + xv.y * wcol[4 * k4 + 1]
                         + xv.z * wcol[4 * k4 + 2] + xv.w * wcol[4 * k4 + 3];
                }
            }
            racc[r] = acc;
            float vs = acc * as, vd = acc * ad;
            #pragma unroll
            for (int off = FOUT / 2; off >= 1; off >>= 1) {
                vs += __shfl_xor(vs, off, 64);
                vd += __shfl_xor(vd, off, 64);
            }
            if (o == 0 && (ROWS * NPT == NN || n < NN)) {
                ses[h * NN + n] = vs; sed[h * NN + n] = vd;
            }
        }
    }
    __syncthreads();
    #pragma unroll
    for (int r = 0; r < ROWS; ++r) {
        int n = n0 + r * NPT;
        if (ROWS * NPT == NN || n < NN) sbuf[n * HF + ho] = racc[r];
    }
    __syncthreads();

    constexpr int FT = FOUT / SPLIT;
    constexpr int ITEMS = H * NN * SPLIT;
    for (int idx = tid; idx < ITEMS; idx += 256) {
        int h2 = idx / (NN * SPLIT);
        int rem = idx % (NN * SPLIT);
        int n = rem / SPLIT;
        int os = (rem % SPLIT) * FT;
        unsigned long long m0 = smask[2 * n], m1 = smask[2 * n + 1];
        float esn = ses[h2 * NN + n];
        float denom = 0.f;
        float acc[FT];
        #pragma unroll
        for (int qq = 0; qq < FT; ++qq) acc[qq] = 0.f;
        const float4* sed4 = (const float4*)&sed[h2 * NN];
        #pragma unroll 2
        for (int g4 = 0; g4 < NN / 4; ++g4) {
            float4 ev = sed4[g4];
            unsigned int bits = (g4 < 16) ? (unsigned int)(m0 >> (4 * g4))
                                          : (unsigned int)(m1 >> (4 * g4 - 64));
            float e0 = esn + ev.x; e0 = (e0 > 0.f) ? e0 : 0.2f * e0;
            float e1 = esn + ev.y; e1 = (e1 > 0.f) ? e1 : 0.2f * e1;
            float e2 = esn + ev.z; e2 = (e2 > 0.f) ? e2 : 0.2f * e2;
            float e3 = esn + ev.w; e3 = (e3 > 0.f) ? e3 : 0.2f * e3;
            float p0 = (bits & 1u) ? __expf(e0) : 0.f;
            float p1 = (bits & 2u) ? __expf(e1) : 0.f;
            float p2 = (bits & 4u) ? __expf(e2) : 0.f;
            float p3 = (bits & 8u) ? __expf(e3) : 0.f;
            denom += (p0 + p1) + (p2 + p3);
            const float* r0 = &sbuf[(4 * g4 + 0) * HF + h2 * FOUT + os];
            const float* r1 = &sbuf[(4 * g4 + 1) * HF + h2 * FOUT + os];
            const float* r2 = &sbuf[(4 * g4 + 2) * HF + h2 * FOUT + os];
            const float* r3 = &sbuf[(4 * g4 + 3) * HF + h2 * FOUT + os];
            #pragma unroll
            for (int q4 = 0; q4 < FT / 4; ++q4) {
                float4 v0 = ((const float4*)r0)[q4];
                float4 v1 = ((const float4*)r1)[q4];
                float4 v2 = ((const float4*)r2)[q4];
                float4 v3 = ((const float4*)r3)[q4];
                acc[4 * q4 + 0] += p0 * v0.x + p1 * v1.x + p2 * v2.x + p3 * v3.x;
                acc[4 * q4 + 1] += p0 * v0.y + p1 * v1.y + p2 * v2.y + p3 * v3.y;
                acc[4 * q4 + 2] += p0 * v0.z + p1 * v1.z + p2 * v2.z + p3 * v3.z;
                acc[4 * q4 + 3] += p0 * v0.w + p1 * v1.w + p2 * v2.w + p3 * v3.w;
            }
        }
        float inv = 1.f / denom;
        if constexpr (OUTMODE == 1) {
            float4* op = (float4*)&out[((size_t)g * NN + n) * FOUT + os];
            #pragma unroll
            for (int q4 = 0; q4 < FT / 4; ++q4) {
                float4 v;
                v.x = acc[4 * q4 + 0] * inv + bias[os + 4 * q4 + 0];
                v.y = acc[4 * q4 + 1] * inv + bias[os + 4 * q4 + 1];
                v.z = acc[4 * q4 + 2] * inv + bias[os + 4 * q4 + 2];
                v.w = acc[4 * q4 + 3] * inv + bias[os + 4 * q4 + 3];
                op[q4] = v;
            }
        } else {
            size_t base = ((size_t)g * NN + n) * FOUT + os;
            float4* op = (float4*)&out[base];
            const float4* mp = (const float4*)&mgate[base];
            #pragma unroll
            for (int q4 = 0; q4 < FT / 4; ++q4) {
                float4 mv = mp[q4];
                float4 v;
                v.x = (acc[4 * q4 + 0] * inv + bias[os + 4 * q4 + 0]) * mv.x;
                v.y = (acc[4 * q4 + 1] * inv + bias[os + 4 * q4 + 1]) * mv.y;
                v.z = (acc[4 * q4 + 2] * inv + bias[os + 4 * q4 + 2]) * mv.z;
                v.w = (acc[4 * q4 + 3] * inv + bias[os + 4 * q4 + 3]) * mv.w;
                op[q4] = v;
            }
        }
    }
}

// ---------------------------------------------------------------- pool + reparameterize
__global__ void pool_kernel(const float* __restrict__ g2, const float* __restrict__ eps,
                            float* __restrict__ z, float* __restrict__ dout) {
    int g = blockIdx.x;
    int c = threadIdx.x;
    __shared__ float s[2 * LATF];
    if (c < 2 * LATF) {
        float sum = 0.f;
        for (int n = 0; n < NN; ++n) sum += g2[((size_t)g * NN + n) * (2 * LATF) + c];
        s[c] = sum * (1.f / NN);
    }
    __syncthreads();
    if (c < LATF) {
        float mu = s[c], lv = s[LATF + c];
        dout[640000 + (size_t)g * LATF + c] = mu;
        dout[652800 + (size_t)g * LATF + c] = lv;
        z[(size_t)g * LATF + c] = mu + eps[(size_t)g * LATF + c] * __expf(0.5f * lv);
    }
}

// ---------------------------------------------------------------- launch
extern "C" void kernel_launch(void* const* d_in, const int* in_sizes, int n_in,
                              void* d_out, int out_size, void* d_ws, size_t ws_size,
                              hipStream_t stream) {
    const float* o     = (const float*)d_in[0];
    const float* aprev = (const float*)d_in[1];
    const float* mk    = (const float*)d_in[2];
    const float* eps   = (const float*)d_in[3];
    const int*   adj   = (const int*)d_in[4];
    const float* Wobs  = (const float*)d_in[5];
    const float* bobs  = (const float*)d_in[6];
    const float* Wpa   = (const float*)d_in[7];
    const float* bpa   = (const float*)d_in[8];
    const float* Wmk   = (const float*)d_in[9];
    const float* bmk   = (const float*)d_in[10];
    const float* idemb = (const float*)d_in[11];
    const float* lWih  = (const float*)d_in[12];
    const float* lWhh  = (const float*)d_in[13];
    const float* lbih  = (const float*)d_in[14];
    const float* lbhh  = (const float*)d_in[15];
    const float* e1w = (const float*)d_in[16]; const float* e1s = (const float*)d_in[17];
    const float* e1d = (const float*)d_in[18]; const float* e1b = (const float*)d_in[19];
    const float* e2w = (const float*)d_in[20]; const float* e2s = (const float*)d_in[21];
    const float* e2d = (const float*)d_in[22]; const float* e2b = (const float*)d_in[23];
    const float* d1w = (const float*)d_in[24]; const float* d1s = (const float*)d_in[25];
    const float* d1d = (const float*)d_in[26]; const float* d1b = (const float*)d_in[27];
    const float* d2w = (const float*)d_in[28]; const float* d2s = (const float*)d_in[29];
    const float* d2d = (const float*)d_in[30]; const float* d2b = (const float*)d_in[31];
    const float* d3w = (const float*)d_in[32]; const float* d3s = (const float*)d_in[33];
    const float* d3d = (const float*)d_in[34]; const float* d3b = (const float*)d_in[35];

    float* ws   = (float*)d_ws;
    float* emb  = ws;
    float* xenc = ws + 5120000;
    float* xW   = ws + 10240000;       // dead after lstm
    float* g1o  = ws + 10240000;       // reuse of xW region
    float* g2o  = ws + 15360000;
    float* z    = ws + 17920000;
    float* d1o  = ws + 18000000;
    float* d2o  = ws + 23200000;
    unsigned long long* amask = (unsigned long long*)(ws + 30720000);
    unsigned* mask32 = (unsigned*)(ws + 30720400);
    float* out = (float*)d_out;

    adjmask_kernel<<<1, 128, 0, stream>>>(adj, amask, mask32);
    emb_kernel<<<BS * TT * NN, 64, 0, stream>>>(o, aprev, mk, Wobs, bobs, Wpa, bpa,
                                                Wmk, bmk, idemb, emb);
    xw_kernel<<<1600 * 5, 256, 0, stream>>>(emb, lWih, lbih, lbhh, xW);
    lstm_kernel<<<1600, 256, 0, stream>>>(xW, lWhh, xenc);
    gat4_mfma_kernel<64, 0><<<800, 256, 0, stream>>>(xenc, nullptr, e1w, e1s, e1d, e1b,
                                                     mask32, g1o);
    gat_kernel<64, 0, 1, 32, 4, 1><<<800, 256, 0, stream>>>(g1o, nullptr, e2w, e2s, e2d, e2b,
                                                            amask, nullptr, g2o);
    pool_kernel<<<800, 64, 0, stream>>>(g2o, eps, z, out);
    gat4_mfma_kernel<64, 16><<<800, 256, 0, stream>>>(emb, z, d1w, d1s, d1d, d1b,
                                                      mask32, d1o);
    gat4_mfma_kernel<64, 0><<<800, 256, 0, stream>>>(d1o, nullptr, d2w, d2s, d2d, d2b,
                                                     mask32, d2o);
    gat_kernel<64, 0, 1, 8, 2, 2><<<800, 256, 0, stream>>>(d2o, nullptr, d3w, d3s, d3d, d3b,
                                                           amask, mk, out);
}

// Round 7
// 514.718 us; speedup vs baseline: 1.2326x; 1.2326x over previous
//
#include <hip/hip_runtime.h>

#define BS  16
#define TT  50
#define NN  100
#define OBSF 40
#define ACTF 8
#define HIDF 64
#define LATF 16

typedef __attribute__((ext_vector_type(8))) short bf16x8;
typedef __attribute__((ext_vector_type(4))) float f32x4;

__device__ __forceinline__ float sigmf(float x) { return 1.f / (1.f + __expf(-x)); }
__device__ __forceinline__ float tanh_fast(float x) { return 1.f - 2.f / (__expf(2.f * x) + 1.f); }
__device__ __forceinline__ short bf16s_rne(float a) {
    unsigned u = __float_as_uint(a); u += 0x7fffu + ((u >> 16) & 1u);
    return (short)(u >> 16);
}
__device__ __forceinline__ unsigned bf16pk_rne(float a, float b) {
    unsigned ua = __float_as_uint(a); ua += 0x7fffu + ((ua >> 16) & 1u);
    unsigned ub = __float_as_uint(b); ub += 0x7fffu + ((ub >> 16) & 1u);
    return (ua >> 16) | (ub & 0xffff0000u);
}

// ---------------------------------------------------------------- adj bitmask
__global__ void adjmask_kernel(const int* __restrict__ adj, unsigned long long* __restrict__ mask) {
    int n = threadIdx.x;
    if (n < NN) {
        unsigned long long w0 = 0ull, w1 = 0ull;
        for (int m = 0; m < 64; ++m)  if (adj[n * NN + m] > 0) w0 |= (1ull << m);
        for (int m = 64; m < NN; ++m) if (adj[n * NN + m] > 0) w1 |= (1ull << (m - 64));
        mask[2 * n] = w0; mask[2 * n + 1] = w1;
    }
}

// ---------------------------------------------------------------- embedding
__global__ void emb_kernel(const float* __restrict__ o, const float* __restrict__ ap,
                           const float* __restrict__ mk,
                           const float* __restrict__ Wobs, const float* __restrict__ bobs,
                           const float* __restrict__ Wpa, const float* __restrict__ bpa,
                           const float* __restrict__ Wmk, const float* __restrict__ bmk,
                           const float* __restrict__ idemb, float* __restrict__ emb) {
    int g = blockIdx.x;               // (b*T+t)*N + n
    int n = g % NN;
    int j = threadIdx.x;              // 0..63
    __shared__ float so[OBSF], sa[ACTF], sm[ACTF];
    if (j < OBSF) so[j] = o[(size_t)g * OBSF + j];
    if (j >= 40 && j < 48) sa[j - 40] = ap[(size_t)g * ACTF + (j - 40)];
    if (j >= 48 && j < 56) sm[j - 48] = mk[(size_t)g * ACTF + (j - 48)];
    __syncthreads();
    float acc = bobs[j] + bpa[j] + bmk[j] + idemb[n * HIDF + j];
    #pragma unroll
    for (int k = 0; k < OBSF; ++k) acc += so[k] * Wobs[k * HIDF + j];
    #pragma unroll
    for (int k = 0; k < ACTF; ++k) acc += sa[k] * Wpa[k * HIDF + j] + sm[k] * Wmk[k * HIDF + j];
    emb[(size_t)g * HIDF + j] = acc;
}

// ---------------------------------------------------------------- MFMA LSTM
// 100 blocks x 16 sequences. Per step t:
//   G[16][256] = Emb_t[16][64]@Wih + H[16][64]@Whh   (16 mfma_16x16x32_bf16)
// Weight B-fragments live in registers (one-time scattered global load,
// L2/L3-hot). G goes through LDS for the cross-wave gate split; gate math is
// spread over all 256 threads (4 units each); c-state in registers; h packed
// bf16 into hbuf (A-fragment source for next step). Emb tile double-buffered
// with register prefetch. Replaces the old xw_kernel + lstm_kernel pair.
__launch_bounds__(256)
__global__ void lstm_mfma_kernel(const float* __restrict__ emb,
                                 const float* __restrict__ Wih, const float* __restrict__ Whh,
                                 const float* __restrict__ bih, const float* __restrict__ bhh,
                                 float* __restrict__ xenc) {
    constexpr int GSTRIDE = 260;                    // gbuf row stride (dwords), 16B-aligned
    __shared__ __align__(16) float gbuf[16 * GSTRIDE];   // 16.6 KB
    __shared__ __align__(16) short embt[2][16 * 72];     // 4.6 KB
    __shared__ __align__(16) short hbuf[16 * 72];        // 2.3 KB

    const int tid = threadIdx.x;
    const int wv = tid >> 6, lane = tid & 63, q = lane >> 4, c = lane & 15;

    // per-thread sequence mapping (used by staging AND gate phase)
    const int seq = tid >> 4;                       // 0..15
    const int part = tid & 15;                      // 0..15
    const int s = blockIdx.x * 16 + seq;
    const int b = s / NN, n = s % NN;
    const size_t ebase = ((size_t)b * (TT * NN) + n) * HIDF + part * 4;  // emb[(b*T+0)*N+n][part*4]
    const int u0 = part * 4;                        // gate-phase unit base
    const size_t xbase = ((size_t)b * (TT * NN) + n) * HIDF + u0;

    // ---- one-time: B-fragments from global (scattered, L2/L3-cached)
    // frag bf[m][kc][nt]: B[k=kc*32+q*8+j][col=wv*64+nt*16+c], m=0:Wih m=1:Whh
    union { short s8[8]; bf16x8 v; } bf[2][2][4];
    {
        const int colb = wv * 64 + c;
        #pragma unroll
        for (int m = 0; m < 2; ++m) {
            const float* W = m ? Whh : Wih;
            #pragma unroll
            for (int kc = 0; kc < 2; ++kc)
                #pragma unroll
                for (int nt = 0; nt < 4; ++nt)
                    #pragma unroll
                    for (int j = 0; j < 8; ++j)
                        bf[m][kc][nt].s8[j] = bf16s_rne(W[(size_t)(kc * 32 + q * 8 + j) * 256 + colb + nt * 16]);
        }
    }
    // gate biases for this thread's 4 units
    float4 bi, bfo, bg, bo;
    {
        float* bp[4] = {&bi.x, &bfo.x, &bg.x, &bo.x};
        #pragma unroll
        for (int gsel = 0; gsel < 4; ++gsel)
            #pragma unroll
            for (int r = 0; r < 4; ++r)
                bp[gsel][r] = bih[gsel * 64 + u0 + r] + bhh[gsel * 64 + u0 + r];
    }
    // zero hbuf; stage embt[0]
    for (int i = tid; i < 16 * 72 / 2; i += 256) ((unsigned*)hbuf)[i] = 0u;
    {
        float4 e0 = *(const float4*)&emb[ebase];
        uint2 pk; pk.x = bf16pk_rne(e0.x, e0.y); pk.y = bf16pk_rne(e0.z, e0.w);
        *(uint2*)&embt[0][seq * 72 + part * 4] = pk;
    }
    float cst[4] = {0.f, 0.f, 0.f, 0.f};
    __syncthreads();

    for (int t = 0; t < TT; ++t) {
        // prefetch emb tile t+1 into regs (latency hidden behind MFMA+gates)
        float4 pre;
        if (t + 1 < TT) pre = *(const float4*)&emb[ebase + (size_t)(t + 1) * (NN * HIDF)];
        // ---- MFMA phase: G = Emb@Wih + H@Whh
        const short* et = &embt[t & 1][0];
        bf16x8 a_e0 = *(const bf16x8*)&et[c * 72 + q * 8];
        bf16x8 a_e1 = *(const bf16x8*)&et[c * 72 + 32 + q * 8];
        bf16x8 a_h0 = *(const bf16x8*)&hbuf[c * 72 + q * 8];
        bf16x8 a_h1 = *(const bf16x8*)&hbuf[c * 72 + 32 + q * 8];
        f32x4 acc[4];
        #pragma unroll
        for (int nt = 0; nt < 4; ++nt) {
            f32x4 a = {0.f, 0.f, 0.f, 0.f};
            a = __builtin_amdgcn_mfma_f32_16x16x32_bf16(a_e0, bf[0][0][nt].v, a, 0, 0, 0);
            a = __builtin_amdgcn_mfma_f32_16x16x32_bf16(a_e1, bf[0][1][nt].v, a, 0, 0, 0);
            a = __builtin_amdgcn_mfma_f32_16x16x32_bf16(a_h0, bf[1][0][nt].v, a, 0, 0, 0);
            a = __builtin_amdgcn_mfma_f32_16x16x32_bf16(a_h1, bf[1][1][nt].v, a, 0, 0, 0);
            acc[nt] = a;
        }
        // C-frag: row(seq)=q*4+r, col=wv*64+nt*16+c
        #pragma unroll
        for (int nt = 0; nt < 4; ++nt)
            #pragma unroll
            for (int r = 0; r < 4; ++r)
                gbuf[(q * 4 + r) * GSTRIDE + wv * 64 + nt * 16 + c] = acc[nt][r];
        __syncthreads();
        // stage prefetched emb into the other buffer (read at t+1, after next barrier)
        if (t + 1 < TT) {
            uint2 pk; pk.x = bf16pk_rne(pre.x, pre.y); pk.y = bf16pk_rne(pre.z, pre.w);
            *(uint2*)&embt[(t + 1) & 1][seq * 72 + part * 4] = pk;
        }
        // ---- gate phase: this thread owns units u0..u0+3 of sequence `seq`
        float4 gi = *(const float4*)&gbuf[seq * GSTRIDE + u0];
        float4 gf = *(const float4*)&gbuf[seq * GSTRIDE + 64 + u0];
        float4 gg = *(const float4*)&gbuf[seq * GSTRIDE + 128 + u0];
        float4 go = *(const float4*)&gbuf[seq * GSTRIDE + 192 + u0];
        float hv[4];
        {
            float gir[4] = {gi.x + bi.x, gi.y + bi.y, gi.z + bi.z, gi.w + bi.w};
            float gfr[4] = {gf.x + bfo.x, gf.y + bfo.y, gf.z + bfo.z, gf.w + bfo.w};
            float ggr[4] = {gg.x + bg.x, gg.y + bg.y, gg.z + bg.z, gg.w + bg.w};
            float gor[4] = {go.x + bo.x, go.y + bo.y, go.z + bo.z, go.w + bo.w};
            #pragma unroll
            for (int r = 0; r < 4; ++r) {
                cst[r] = sigmf(gfr[r]) * cst[r] + sigmf(gir[r]) * tanh_fast(ggr[r]);
                hv[r] = sigmf(gor[r]) * tanh_fast(cst[r]);
            }
        }
        // h -> hbuf (bf16) and xenc (fp32, coalesced float4)
        uint2 hpk; hpk.x = bf16pk_rne(hv[0], hv[1]); hpk.y = bf16pk_rne(hv[2], hv[3]);
        *(uint2*)&hbuf[seq * 72 + u0] = hpk;
        float4 xo; xo.x = hv[0]; xo.y = hv[1]; xo.z = hv[2]; xo.w = hv[3];
        *(float4*)&xenc[xbase + (size_t)t * (NN * HIDF)] = xo;
        __syncthreads();
    }
}

// ---------------------------------------------------------------- fused GAT layer (round-2 VALU)
// OUTMODE 0: concat heads + elu(+bias); 1: single head + bias; 2: +bias then * mgate
template <int FIN1, int FIN2, int H, int FOUT, int SPLIT, int OUTMODE>
__launch_bounds__(256)
__global__ void gat_kernel(const float* __restrict__ x1, const float* __restrict__ x2,
                           const float* __restrict__ w, const float* __restrict__ asrc,
                           const float* __restrict__ adst, const float* __restrict__ bias,
                           const unsigned long long* __restrict__ adjmask,
                           const float* __restrict__ mgate, float* __restrict__ out) {
    constexpr int FIN = FIN1 + FIN2;
    constexpr int HF = H * FOUT;
    constexpr int NPT = 256 / HF;
    constexpr int ROWS = (NN + NPT - 1) / NPT;
    constexpr int SB = NN * (FIN > HF ? FIN : HF);
    __shared__ __align__(16) float sbuf[SB];
    __shared__ __align__(16) float ses[H * NN];
    __shared__ __align__(16) float sed[H * NN];
    __shared__ unsigned long long smask[2 * NN];
    int g = blockIdx.x;
    int tid = threadIdx.x;

    for (int i = tid; i < NN * FIN1; i += 256) {
        int n = i / FIN1, k = i % FIN1;
        sbuf[n * FIN + k] = x1[((size_t)g * NN + n) * FIN1 + k];
    }
    if constexpr (FIN2 > 0) {
        for (int i = tid; i < NN * FIN2; i += 256) {
            int n = i / FIN2, k = i % FIN2;
            sbuf[n * FIN + FIN1 + k] = x2[(size_t)g * FIN2 + k];
        }
    }
    if (tid < 2 * NN) smask[tid] = adjmask[tid];
    __syncthreads();

    const int ho = tid % HF;
    const int h = ho / FOUT, o = ho % FOUT;
    const int n0 = tid / HF;
    float racc[ROWS];
    {
        float wcol[FIN];
        #pragma unroll
        for (int k = 0; k < FIN; ++k) wcol[k] = w[(h * FIN + k) * FOUT + o];
        const float as = asrc[ho], ad = adst[ho];
        #pragma unroll
        for (int r = 0; r < ROWS; ++r) {
            int n = n0 + r * NPT;
            float acc = 0.f;
            if (ROWS * NPT == NN || n < NN) {
                const float4* row = (const float4*)&sbuf[n * FIN];
                #pragma unroll
                for (int k4 = 0; k4 < FIN / 4; ++k4) {
                    float4 xv = row[k4];
                    acc += xv.x * wcol[4 * k4] + xv.y * wcol[4 * k4 + 1]
                         + xv.z * wcol[4 * k4 + 2] + xv.w * wcol[4 * k4 + 3];
                }
            }
            racc[r] = acc;
            float vs = acc * as, vd = acc * ad;
            #pragma unroll
            for (int off = FOUT / 2; off >= 1; off >>= 1) {
                vs += __shfl_xor(vs, off, 64);
                vd += __shfl_xor(vd, off, 64);
            }
            if (o == 0 && (ROWS * NPT == NN || n < NN)) {
                ses[h * NN + n] = vs; sed[h * NN + n] = vd;
            }
        }
    }
    __syncthreads();
    #pragma unroll
    for (int r = 0; r < ROWS; ++r) {
        int n = n0 + r * NPT;
        if (ROWS * NPT == NN || n < NN) sbuf[n * HF + ho] = racc[r];
    }
    __syncthreads();

    constexpr int FT = FOUT / SPLIT;
    constexpr int ITEMS = H * NN * SPLIT;
    for (int idx = tid; idx < ITEMS; idx += 256) {
        int h2 = idx / (NN * SPLIT);
        int rem = idx % (NN * SPLIT);
        int n = rem / SPLIT;
        int os = (rem % SPLIT) * FT;
        unsigned long long m0 = smask[2 * n], m1 = smask[2 * n + 1];
        float esn = ses[h2 * NN + n];
        float denom = 0.f;
        float acc[FT];
        #pragma unroll
        for (int qq = 0; qq < FT; ++qq) acc[qq] = 0.f;
        const float4* sed4 = (const float4*)&sed[h2 * NN];
        #pragma unroll 2
        for (int g4 = 0; g4 < NN / 4; ++g4) {
            float4 ev = sed4[g4];
            unsigned int bits = (g4 < 16) ? (unsigned int)(m0 >> (4 * g4))
                                          : (unsigned int)(m1 >> (4 * g4 - 64));
            float e0 = esn + ev.x; e0 = (e0 > 0.f) ? e0 : 0.2f * e0;
            float e1 = esn + ev.y; e1 = (e1 > 0.f) ? e1 : 0.2f * e1;
            float e2 = esn + ev.z; e2 = (e2 > 0.f) ? e2 : 0.2f * e2;
            float e3 = esn + ev.w; e3 = (e3 > 0.f) ? e3 : 0.2f * e3;
            float p0 = (bits & 1u) ? __expf(e0) : 0.f;
            float p1 = (bits & 2u) ? __expf(e1) : 0.f;
            float p2 = (bits & 4u) ? __expf(e2) : 0.f;
            float p3 = (bits & 8u) ? __expf(e3) : 0.f;
            denom += (p0 + p1) + (p2 + p3);
            const float* r0 = &sbuf[(4 * g4 + 0) * HF + h2 * FOUT + os];
            const float* r1 = &sbuf[(4 * g4 + 1) * HF + h2 * FOUT + os];
            const float* r2 = &sbuf[(4 * g4 + 2) * HF + h2 * FOUT + os];
            const float* r3 = &sbuf[(4 * g4 + 3) * HF + h2 * FOUT + os];
            #pragma unroll
            for (int q4 = 0; q4 < FT / 4; ++q4) {
                float4 v0 = ((const float4*)r0)[q4];
                float4 v1 = ((const float4*)r1)[q4];
                float4 v2 = ((const float4*)r2)[q4];
                float4 v3 = ((const float4*)r3)[q4];
                acc[4 * q4 + 0] += p0 * v0.x + p1 * v1.x + p2 * v2.x + p3 * v3.x;
                acc[4 * q4 + 1] += p0 * v0.y + p1 * v1.y + p2 * v2.y + p3 * v3.y;
                acc[4 * q4 + 2] += p0 * v0.z + p1 * v1.z + p2 * v2.z + p3 * v3.z;
                acc[4 * q4 + 3] += p0 * v0.w + p1 * v1.w + p2 * v2.w + p3 * v3.w;
            }
        }
        float inv = 1.f / denom;
        if constexpr (OUTMODE == 0) {
            float4* op = (float4*)&out[((size_t)g * NN + n) * HF + h2 * FOUT + os];
            #pragma unroll
            for (int q4 = 0; q4 < FT / 4; ++q4) {
                float4 v;
                float a0 = acc[4 * q4 + 0] * inv + bias[h2 * FOUT + os + 4 * q4 + 0];
                float a1 = acc[4 * q4 + 1] * inv + bias[h2 * FOUT + os + 4 * q4 + 1];
                float a2 = acc[4 * q4 + 2] * inv + bias[h2 * FOUT + os + 4 * q4 + 2];
                float a3 = acc[4 * q4 + 3] * inv + bias[h2 * FOUT + os + 4 * q4 + 3];
                v.x = (a0 > 0.f) ? a0 : (__expf(a0) - 1.f);
                v.y = (a1 > 0.f) ? a1 : (__expf(a1) - 1.f);
                v.z = (a2 > 0.f) ? a2 : (__expf(a2) - 1.f);
                v.w = (a3 > 0.f) ? a3 : (__expf(a3) - 1.f);
                op[q4] = v;
            }
        } else if constexpr (OUTMODE == 1) {
            float4* op = (float4*)&out[((size_t)g * NN + n) * FOUT + os];
            #pragma unroll
            for (int q4 = 0; q4 < FT / 4; ++q4) {
                float4 v;
                v.x = acc[4 * q4 + 0] * inv + bias[os + 4 * q4 + 0];
                v.y = acc[4 * q4 + 1] * inv + bias[os + 4 * q4 + 1];
                v.z = acc[4 * q4 + 2] * inv + bias[os + 4 * q4 + 2];
                v.w = acc[4 * q4 + 3] * inv + bias[os + 4 * q4 + 3];
                op[q4] = v;
            }
        } else {
            size_t base = ((size_t)g * NN + n) * FOUT + os;
            float4* op = (float4*)&out[base];
            const float4* mp = (const float4*)&mgate[base];
            #pragma unroll
            for (int q4 = 0; q4 < FT / 4; ++q4) {
                float4 mv = mp[q4];
                float4 v;
                v.x = (acc[4 * q4 + 0] * inv + bias[os + 4 * q4 + 0]) * mv.x;
                v.y = (acc[4 * q4 + 1] * inv + bias[os + 4 * q4 + 1]) * mv.y;
                v.z = (acc[4 * q4 + 2] * inv + bias[os + 4 * q4 + 2]) * mv.z;
                v.w = (acc[4 * q4 + 3] * inv + bias[os + 4 * q4 + 3]) * mv.w;
                op[q4] = v;
            }
        }
    }
}

// ---------------------------------------------------------------- pool + reparameterize
__global__ void pool_kernel(const float* __restrict__ g2, const float* __restrict__ eps,
                            float* __restrict__ z, float* __restrict__ dout) {
    int g = blockIdx.x;
    int c = threadIdx.x;
    __shared__ float s[2 * LATF];
    if (c < 2 * LATF) {
        float sum = 0.f;
        for (int n = 0; n < NN; ++n) sum += g2[((size_t)g * NN + n) * (2 * LATF) + c];
        s[c] = sum * (1.f / NN);
    }
    __syncthreads();
    if (c < LATF) {
        float mu = s[c], lv = s[LATF + c];
        dout[640000 + (size_t)g * LATF + c] = mu;
        dout[652800 + (size_t)g * LATF + c] = lv;
        z[(size_t)g * LATF + c] = mu + eps[(size_t)g * LATF + c] * __expf(0.5f * lv);
    }
}

// ---------------------------------------------------------------- launch
extern "C" void kernel_launch(void* const* d_in, const int* in_sizes, int n_in,
                              void* d_out, int out_size, void* d_ws, size_t ws_size,
                              hipStream_t stream) {
    const float* o     = (const float*)d_in[0];
    const float* aprev = (const float*)d_in[1];
    const float* mk    = (const float*)d_in[2];
    const float* eps   = (const float*)d_in[3];
    const int*   adj   = (const int*)d_in[4];
    const float* Wobs  = (const float*)d_in[5];
    const float* bobs  = (const float*)d_in[6];
    const float* Wpa   = (const float*)d_in[7];
    const float* bpa   = (const float*)d_in[8];
    const float* Wmk   = (const float*)d_in[9];
    const float* bmk   = (const float*)d_in[10];
    const float* idemb = (const float*)d_in[11];
    const float* lWih  = (const float*)d_in[12];
    const float* lWhh  = (const float*)d_in[13];
    const float* lbih  = (const float*)d_in[14];
    const float* lbhh  = (const float*)d_in[15];
    const float* e1w = (const float*)d_in[16]; const float* e1s = (const float*)d_in[17];
    const float* e1d = (const float*)d_in[18]; const float* e1b = (const float*)d_in[19];
    const float* e2w = (const float*)d_in[20]; const float* e2s = (const float*)d_in[21];
    const float* e2d = (const float*)d_in[22]; const float* e2b = (const float*)d_in[23];
    const float* d1w = (const float*)d_in[24]; const float* d1s = (const float*)d_in[25];
    const float* d1d = (const float*)d_in[26]; const float* d1b = (const float*)d_in[27];
    const float* d2w = (const float*)d_in[28]; const float* d2s = (const float*)d_in[29];
    const float* d2d = (const float*)d_in[30]; const float* d2b = (const float*)d_in[31];
    const float* d3w = (const float*)d_in[32]; const float* d3s = (const float*)d_in[33];
    const float* d3d = (const float*)d_in[34]; const float* d3b = (const float*)d_in[35];

    float* ws   = (float*)d_ws;
    float* emb  = ws;
    float* xenc = ws + 5120000;
    float* g1o  = ws + 10240000;
    float* g2o  = ws + 15360000;
    float* z    = ws + 17920000;
    float* d1o  = ws + 18000000;
    float* d2o  = ws + 23200000;
    unsigned long long* amask = (unsigned long long*)(ws + 30720000);
    float* out = (float*)d_out;

    adjmask_kernel<<<1, 128, 0, stream>>>(adj, amask);
    emb_kernel<<<BS * TT * NN, 64, 0, stream>>>(o, aprev, mk, Wobs, bobs, Wpa, bpa,
                                                Wmk, bmk, idemb, emb);
    lstm_mfma_kernel<<<100, 256, 0, stream>>>(emb, lWih, lWhh, lbih, lbhh, xenc);
    gat_kernel<64, 0, 4, 16, 1, 0><<<800, 256, 0, stream>>>(xenc, nullptr, e1w, e1s, e1d, e1b,
                                                            amask, nullptr, g1o);
    gat_kernel<64, 0, 1, 32, 4, 1><<<800, 256, 0, stream>>>(g1o, nullptr, e2w, e2s, e2d, e2b,
                                                            amask, nullptr, g2o);
    pool_kernel<<<800, 64, 0, stream>>>(g2o, eps, z, out);
    gat_kernel<64, 16, 4, 16, 1, 0><<<800, 256, 0, stream>>>(emb, z, d1w, d1s, d1d, d1b,
                                                             amask, nullptr, d1o);
    gat_kernel<64, 0, 4, 16, 1, 0><<<800, 256, 0, stream>>>(d1o, nullptr, d2w, d2s, d2d, d2b,
                                                            amask, nullptr, d2o);
    gat_kernel<64, 0, 1, 8, 2, 2><<<800, 256, 0, stream>>>(d2o, nullptr, d3w, d3s, d3d, d3b,
                                                           amask, mk, out);
}